// Round 7
// baseline (207.104 us; speedup 1.0000x reference)
//
#include <hip/hip_runtime.h>
#include <hip/hip_bf16.h>

// Problem constants
#define QSTRIDE 147584   // per-sample question_rep stride (128*128*9 + 128)
#define WOFF    147456   // bias offset within question_rep row

typedef __attribute__((ext_vector_type(8))) short bf16x8;
typedef __attribute__((ext_vector_type(4))) float f32x4;

static __device__ __forceinline__ ushort f2bf(float f) {
  union { float f; unsigned u; } x; x.f = f;
  unsigned r = x.u + 0x7fffu + ((x.u >> 16) & 1u);  // RNE bf16 (finite inputs)
  return (ushort)(r >> 16);
}
static __device__ __forceinline__ unsigned pk2(ushort a, ushort b) {
  return (unsigned)a | ((unsigned)b << 16);
}
// async global->LDS DMA: 16B per active lane, lands at ldsbase + lane*16
static __device__ __forceinline__ void async16(const ushort* g, ushort* l) {
  __builtin_amdgcn_global_load_lds((const __attribute__((address_space(1))) void*)g,
                                   (__attribute__((address_space(3))) void*)l, 16, 0, 0);
}
// barrier with counted vmcnt + full LDS drain (lgkm0 closes cross-wave WAR
// on LDS ring buffers -- round-2 lesson). vmcnt counted so DMAs stay in flight.
#define WAITBAR_(vm) asm volatile("s_waitcnt vmcnt(" #vm ") lgkmcnt(0)\n\ts_barrier" ::: "memory")
#define WAITBAR(vm) WAITBAR_(vm)
#define BARSYNC() asm volatile("s_waitcnt lgkmcnt(0)\n\ts_barrier" ::: "memory")

// ---------------------------------------------------------------------------
// 1) question_rep weights -> wt2[b][tap][cq][o][ci32] bf16  (R6, verified)
// ---------------------------------------------------------------------------
__global__ __launch_bounds__(256) void pack_w_kernel(const float* __restrict__ q,
                                                     ushort* __restrict__ wt2) {
  __shared__ float  Ls[4608];
  __shared__ ushort Lw[9 * 4 * 16 * 32];
  int b = blockIdx.x >> 3, ogrp = blockIdx.x & 7;
  int t = threadIdx.x;
  const float* gbase = q + (size_t)b * QSTRIDE + (size_t)ogrp * 16 * 1152;
  int o_loc = t >> 6;
  int ci    = (t & 63) * 2;
  int cq    = ci >> 5, coff = ci & 31;
  for (int r = 0; r < 4; ++r) {
    __syncthreads();
    const float* gs = gbase + r * 4608;
#pragma unroll
    for (int i = 0; i < 18; ++i) Ls[i * 256 + t] = gs[i * 256 + t];
    __syncthreads();
    int o_in = r * 4 + o_loc;
    const float* v = Ls + o_loc * 1152 + ci * 9;
    float a[18];
#pragma unroll
    for (int i = 0; i < 18; ++i) a[i] = v[i];
#pragma unroll
    for (int tap = 0; tap < 9; ++tap) {
      unsigned pkv = pk2(f2bf(a[tap]), f2bf(a[9 + tap]));
      *(unsigned*)&Lw[((tap * 4 + cq) * 16 + o_in) * 32 + coff] = pkv;
    }
  }
  __syncthreads();
  int wv = t >> 6, l = t & 63;
  ushort* dstb = wt2 + (size_t)b * 147456 + (size_t)ogrp * 16 * 32;
#pragma unroll
  for (int tap = 0; tap < 9; ++tap) {
    const uint4 val = *(const uint4*)&Lw[(tap * 4 + wv) * 512 + l * 8];
    *(uint4*)(dstb + (size_t)(tap * 4 + wv) * 4096 + l * 8) = val;
  }
}

// ---------------------------------------------------------------------------
// 2) proj_w -> pwb2[chunk][o][c32] bf16  (R6, verified)
// ---------------------------------------------------------------------------
__global__ __launch_bounds__(256) void pack_pw_kernel(const float* __restrict__ pw,
                                                      ushort* __restrict__ pwb2) {
  int tg = blockIdx.x * 256 + threadIdx.x;
  int o  = tg >> 5;
  int c0 = (tg & 31) * 8;
  const float4* s4 = (const float4*)(pw + (size_t)o * 256 + c0);
  float4 f0 = s4[0], f1 = s4[1];
  uint4 pkv;
  pkv.x = pk2(f2bf(f0.x), f2bf(f0.y)); pkv.y = pk2(f2bf(f0.z), f2bf(f0.w));
  pkv.z = pk2(f2bf(f1.x), f2bf(f1.y)); pkv.w = pk2(f2bf(f1.z), f2bf(f1.w));
  *(uint4*)(pwb2 + (size_t)(c0 >> 5) * 4096 + o * 32 + (c0 & 31)) = pkv;
}

// ---------------------------------------------------------------------------
// 3) transpose_x: lhs/rhs fp32 NCHW -> xt[b][c8][px1024][ch32] bf16 (R6, verified)
// ---------------------------------------------------------------------------
__global__ __launch_bounds__(256) void transpose_x_kernel(const float* __restrict__ lhs,
                                                          const float* __restrict__ rhs,
                                                          ushort* __restrict__ xt) {
  __shared__ ushort Ts[32][132];
  int b = blockIdx.y;
  int c = blockIdx.x & 7, half = blockIdx.x >> 3;
  const float* src = (c < 4 ? lhs : rhs) + (size_t)b * 131072 + (size_t)(c & 3) * 32768;
  ushort* dst = xt + (size_t)(b * 8 + c) * 32768;
  int t = threadIdx.x;
  int chw = t >> 3, pxg = (t & 7) * 16;
  int pxr = t >> 1, chr = (t & 1) * 16;
#pragma unroll
  for (int pt = 0; pt < 4; ++pt) {
    int p0 = half * 512 + pt * 128;
    if (pt) __syncthreads();
    const float* s = src + (size_t)chw * 1024 + p0 + pxg;
#pragma unroll
    for (int i = 0; i < 4; ++i) {
      float4 f = *(const float4*)(s + 4 * i);
      uint2 pk;
      pk.x = pk2(f2bf(f.x), f2bf(f.y));
      pk.y = pk2(f2bf(f.z), f2bf(f.w));
      *(uint2*)&Ts[chw][pxg + 4 * i] = pk;
    }
    __syncthreads();
    ushort g[16];
#pragma unroll
    for (int j = 0; j < 16; ++j) g[j] = Ts[chr + j][pxr];
    *(uint4*)(dst + (size_t)(p0 + pxr) * 32 + chr)     = *(uint4*)&g[0];
    *(uint4*)(dst + (size_t)(p0 + pxr) * 32 + chr + 8) = *(uint4*)&g[8];
  }
}

// ---------------------------------------------------------------------------
// 4) FUSED proj+conv v3: deep-MLP via global_load_lds bursts.
//    Little's-law fix: ~22 KB/CU of loads must be in flight for peak HBM BW;
//    VGPR loads max out at ~1-2 KB. DMAs hold no VGPRs and queue 63-deep.
//    phase 0: burst-DMA whole xt patch (24 instr/wave = 24 KB/wave in flight)
//             + first 4 wt2 A-slabs. WAITBAR(8) -> patch landed, A in flight.
//    phase 1: mini-proj GEMM; bg via conflict-free ds_read_b128 from Xs;
//             af from L2-hot pwb2. acc[3][8] in regs.
//    epilogue: Bs ALIASES dead Xs (barrier-protected), halo zeroed.
//    phase 2: 36 steps; A-slabs stream through a depth-5 LDS ring with
//             counted vmcnt (never 0 until the tail). Depth 5 => slab s+4
//             issued at step-s top only collides with slab s-1's slot, whose
//             reads completed at this barrier (lgkm0). vm derivation:
//             after issue, outstanding = slabs [s+1..s+4] = 8 DMAs; next
//             step's WAITBAR(6) retires slab s+1. Tail 4/2/0.
//    LDS 139,264 B -> 1 block/CU; BW comes from DMA depth, not waves.
// ---------------------------------------------------------------------------
__global__ __launch_bounds__(256, 1) void fused_conv_kernel(const ushort* __restrict__ wt2,
                                                            const ushort* __restrict__ pwb2,
                                                            const ushort* __restrict__ xt,
                                                            const float* __restrict__ pb,
                                                            const float* __restrict__ q,
                                                            float* __restrict__ out) {
  __shared__ ushort LDSP[69632];             // 139,264 B
  ushort* Xs = LDSP;                         // [8][192][32] bf16 = 98,304 B
  ushort* Bs = LDSP;                         // alias: [4][6][34][32] = 52,224 B
  ushort* Ar = LDSP + 49152;                 // ring [5][4096] = 40,960 B
#define BSOFF(cq, r, p, ch) ((((cq) * 6 + (r)) * 34 + (p)) * 32 + (ch))
  int blk = blockIdx.x;
  int b = blk & 63, tile = blk >> 6;
  int p0 = tile * 128, h0 = tile * 4;
  int t = threadIdx.x;
  int lane = t & 63, wv = t >> 6;
  int quad = lane >> 4, li = lane & 15;
  const ushort* wtb = wtb = wt2 + (size_t)b * 147456;
  const ushort* xtb = xt + (size_t)b * 8 * 32768;

  // ---- phase 0: DMA bursts ----
  // Xs: wave wv stages chunks {wv, wv+4}; 12 DMA/chunk (16 px = 1 KB each).
  // Source rows clamped to [0,31]; dead rows carry junk, never read (lv mask).
#pragma unroll
  for (int cc = 0; cc < 2; ++cc) {
    int c = wv + cc * 4;
    const ushort* xs = xtb + (size_t)c * 32768;
    ushort* xd = Xs + c * 6144;
#pragma unroll
    for (int i = 0; i < 12; ++i) {
      int r = i >> 1;                        // patch row 0..5
      int h = h0 - 1 + r; h = h < 0 ? 0 : (h > 31 ? 31 : h);
      int pxg = h * 32 + (i & 1) * 16;       // 16-px group
      async16(xs + (size_t)pxg * 32 + lane * 8, xd + i * 512);
    }
  }
  // A slabs 0..3 (s = cq*9+tap order: cq=0, taps 0..3): 2 DMA/wave each
#pragma unroll
  for (int s = 0; s < 4; ++s) {
    const ushort* ag = wtb + (size_t)((s % 9) * 4 + (s / 9)) * 4096;
    ushort* ad = Ar + (s % 5) * 4096 + wv * 1024;
    async16(ag + (size_t)(wv * 2) * 512 + lane * 8,       ad);
    async16(ag + (size_t)(wv * 2 + 1) * 512 + lane * 8,   ad + 512);
  }
  WAITBAR(8);                                // Xs landed; A slabs 0-3 in flight

  // ---- phase 1: mini-proj into acc ----
  int rk[3], wk[3]; bool lv[3];
#pragma unroll
  for (int k = 0; k < 3; ++k) {
    int nt = wv * 3 + k;
    rk[k] = nt >> 1;                         // patch row 0..5
    wk[k] = (nt & 1) * 16;                   // w base 0 or 16
    int hk = h0 - 1 + rk[k];
    lv[k] = (hk >= 0) && (hk < 32);
  }
  f32x4 acc[3][8] = {};
#pragma unroll
  for (int c = 0; c < 8; ++c) {
    bf16x8 bg[3];
#pragma unroll
    for (int k = 0; k < 3; ++k) {
      union { uint4 u; bf16x8 v; } bu;
      if (lv[k]) {
        int pl = rk[k] * 32 + wk[k] + li;    // patch-local px 0..191
        bu.u = *(const uint4*)(Xs + (size_t)c * 6144 + pl * 32 + quad * 8);
      } else {
        bu.u.x = bu.u.y = bu.u.z = bu.u.w = 0u;
      }
      bg[k] = bu.v;
    }
    const ushort* ap = pwb2 + (size_t)c * 4096 + li * 32 + quad * 8;
#pragma unroll
    for (int mi = 0; mi < 8; ++mi) {
      bf16x8 af = *(const bf16x8*)(ap + mi * 512);
#pragma unroll
      for (int k = 0; k < 3; ++k)
        acc[k][mi] = __builtin_amdgcn_mfma_f32_16x16x32_bf16(af, bg[k], acc[k][mi], 0, 0, 0);
    }
  }

  BARSYNC();                                 // all Xs reads done -> Bs may alias

  // ---- epilogue into Bs (aliases Xs) + halo zero ----
  if (t < 48) {
    int cq = t & 3, side = (t >> 2) & 1, rr = t >> 3;
    uint4* z4 = (uint4*)&Bs[BSOFF(cq, rr, side ? 33 : 0, 0)];
    uint4 z; z.x = z.y = z.z = z.w = 0u;
    z4[0] = z; z4[1] = z; z4[2] = z; z4[3] = z;
  }
#pragma unroll
  for (int k = 0; k < 3; ++k) {
#pragma unroll
    for (int mi = 0; mi < 8; ++mi) {
      int o0 = mi * 16 + quad * 4;
      uint2 pkv;
      if (lv[k]) {
        float4 bias = *(const float4*)(pb + o0);
        f32x4 a = acc[k][mi];
        pkv.x = pk2(f2bf(a.x + bias.x), f2bf(a.y + bias.y));
        pkv.y = pk2(f2bf(a.z + bias.z), f2bf(a.w + bias.w));
      } else {
        pkv.x = 0u; pkv.y = 0u;
      }
      *(uint2*)&Bs[BSOFF(o0 >> 5, rk[k], wk[k] + li + 1, o0 & 31)] = pkv;
    }
  }
  BARSYNC();                                 // Bs fully built & visible

  // ---- phase 2: 36 (cq,tap) steps; A via depth-5 ring, counted vmcnt ----
  int m0 = (wv & 1) * 64, n0 = (wv >> 1) * 64;
  f32x4 acc2[4][4] = {};

#define CSTEP(s, vm) do { \
    WAITBAR(vm); \
    if ((s) + 4 <= 35) { \
      const int sn = (s) + 4; \
      const ushort* ag = wtb + (size_t)((sn % 9) * 4 + (sn / 9)) * 4096; \
      ushort* ad = Ar + (sn % 5) * 4096 + wv * 1024; \
      async16(ag + (size_t)(wv * 2) * 512 + lane * 8,     ad); \
      async16(ag + (size_t)(wv * 2 + 1) * 512 + lane * 8, ad + 512); \
    } \
    __builtin_amdgcn_sched_barrier(0); \
    { const int cq_ = (s) / 9, tap_ = (s) % 9; \
      const int kh_ = tap_ / 3, kw_ = tap_ % 3; \
      const ushort* ar = Ar + ((s) % 5) * 4096; \
      bf16x8 af[4], bg[4]; \
      _Pragma("unroll") \
      for (int mi = 0; mi < 4; ++mi) \
        af[mi] = *(const bf16x8*)(ar + (m0 + mi*16 + li) * 32 + quad * 8); \
      _Pragma("unroll") \
      for (int ni = 0; ni < 4; ++ni) { \
        int pl = n0 + ni*16 + li; \
        int hh = pl >> 5, ww = pl & 31; \
        bg[ni] = *(const bf16x8*)&Bs[BSOFF(cq_, hh + kh_, ww + kw_, quad * 8)]; \
      } \
      _Pragma("unroll") \
      for (int mi = 0; mi < 4; ++mi) \
        _Pragma("unroll") \
        for (int ni = 0; ni < 4; ++ni) \
          acc2[mi][ni] = __builtin_amdgcn_mfma_f32_16x16x32_bf16(af[mi], bg[ni], acc2[mi][ni], 0, 0, 0); \
    } \
  } while (0)

  CSTEP( 0,6); CSTEP( 1,6); CSTEP( 2,6); CSTEP( 3,6); CSTEP( 4,6); CSTEP( 5,6);
  CSTEP( 6,6); CSTEP( 7,6); CSTEP( 8,6); CSTEP( 9,6); CSTEP(10,6); CSTEP(11,6);
  CSTEP(12,6); CSTEP(13,6); CSTEP(14,6); CSTEP(15,6); CSTEP(16,6); CSTEP(17,6);
  CSTEP(18,6); CSTEP(19,6); CSTEP(20,6); CSTEP(21,6); CSTEP(22,6); CSTEP(23,6);
  CSTEP(24,6); CSTEP(25,6); CSTEP(26,6); CSTEP(27,6); CSTEP(28,6); CSTEP(29,6);
  CSTEP(30,6); CSTEP(31,6); CSTEP(32,6); CSTEP(33,4); CSTEP(34,2); CSTEP(35,0);
#undef CSTEP

  const float* qb = q + (size_t)b * QSTRIDE + WOFF;
  float* ob = out + (size_t)b * 128 * 1024 + p0;
#pragma unroll
  for (int mi = 0; mi < 4; ++mi) {
    int o0 = m0 + mi*16 + quad*4;
    float4 bias = *(const float4*)(qb + o0);
#pragma unroll
    for (int ni = 0; ni < 4; ++ni) {
      int pl = n0 + ni*16 + li;
      float* dp = ob + (size_t)o0 * 1024 + pl;
      f32x4 a = acc2[mi][ni];
      dp[0]    = a.x + bias.x;
      dp[1024] = a.y + bias.y;
      dp[2048] = a.z + bias.z;
      dp[3072] = a.w + bias.w;
    }
  }
#undef BSOFF
}

extern "C" void kernel_launch(void* const* d_in, const int* in_sizes, int n_in,
                              void* d_out, int out_size, void* d_ws, size_t ws_size,
                              hipStream_t stream) {
  const float* q   = (const float*)d_in[0];
  const float* lhs = (const float*)d_in[1];
  const float* rhs = (const float*)d_in[2];
  const float* pw  = (const float*)d_in[3];
  const float* pb  = (const float*)d_in[4];
  float* out = (float*)d_out;

  // workspace layout (52,494,336 B used)
  char* ws = (char*)d_ws;
  ushort* wt2  = (ushort*)(ws);               // 18,874,368 B : wt2[b][tap][cq][o][32]
  ushort* pwb2 = (ushort*)(ws + 18874368);    //     65,536 B : pwb2[chunk][o][32]
  ushort* xt   = (ushort*)(ws + 18939904);    // 33,554,432 B : xt[b][c8][px1024][ch32]

  pack_w_kernel     <<<512, 256, 0, stream>>>(q, wt2);
  pack_pw_kernel    <<<16,  256, 0, stream>>>(pw, pwb2);
  transpose_x_kernel<<<dim3(16, 64), 256, 0, stream>>>(lhs, rhs, xt);
  fused_conv_kernel <<<512, 256, 0, stream>>>(wt2, pwb2, xt, pb, q, out);
}

// Round 8
// 182.421 us; speedup vs baseline: 1.1353x; 1.1353x over previous
//
#include <hip/hip_runtime.h>
#include <hip/hip_bf16.h>

// Problem constants
#define QSTRIDE 147584   // per-sample question_rep stride (128*128*9 + 128)
#define WOFF    147456   // bias offset within question_rep row

typedef __attribute__((ext_vector_type(8))) short bf16x8;
typedef __attribute__((ext_vector_type(4))) float f32x4;

static __device__ __forceinline__ ushort f2bf(float f) {
  union { float f; unsigned u; } x; x.f = f;
  unsigned r = x.u + 0x7fffu + ((x.u >> 16) & 1u);  // RNE bf16 (finite inputs)
  return (ushort)(r >> 16);
}
static __device__ __forceinline__ unsigned pk2(ushort a, ushort b) {
  return (unsigned)a | ((unsigned)b << 16);
}

// ---------------------------------------------------------------------------
// 1) MERGED prep kernel. Three independent memory-bound preps run in ONE
//    dispatch so they share the machine (they were serial before: ~77 us +
//    2 launch gaps). Block ranges:
//      [0,1024)    transpose_x : lhs/rhs fp32 NCHW -> xt[b][c8][px1024][ch32]
//      [1024,1536) pack_w      : question_rep -> wt2[b][tap][cq][o][ci32]
//                                (reads now float4-vectorized, identity map)
//      [1536,1552) pack_pw     : proj_w -> pwb2[chunk][o][c32]
//    Shared mem is a 55,296 B union (pack_w: Ls+Lw; transpose: Ts)
//    -> 2 blocks/CU for every branch.
// ---------------------------------------------------------------------------
__global__ __launch_bounds__(256) void prep_kernel(const float* __restrict__ q,
                                                   const float* __restrict__ pw,
                                                   const float* __restrict__ lhs,
                                                   const float* __restrict__ rhs,
                                                   ushort* __restrict__ wt2,
                                                   ushort* __restrict__ pwb2,
                                                   ushort* __restrict__ xt) {
  __shared__ __attribute__((aligned(16))) char smem[55296];
  int blk = blockIdx.x;
  int t = threadIdx.x;

  if (blk < 1024) {
    // ---- transpose_x (verified R6 body) ----
    ushort (*Ts)[132] = (ushort(*)[132])smem;      // 32 x 132 x 2B = 8448 B
    int b = blk >> 4, x = blk & 15;
    int c = x & 7, half = x >> 3;
    const float* src = (c < 4 ? lhs : rhs) + (size_t)b * 131072 + (size_t)(c & 3) * 32768;
    ushort* dst = xt + (size_t)(b * 8 + c) * 32768;
    int chw = t >> 3, pxg = (t & 7) * 16;
    int pxr = t >> 1, chr = (t & 1) * 16;
#pragma unroll
    for (int pt = 0; pt < 4; ++pt) {
      int p0 = half * 512 + pt * 128;
      if (pt) __syncthreads();
      const float* s = src + (size_t)chw * 1024 + p0 + pxg;
#pragma unroll
      for (int i = 0; i < 4; ++i) {
        float4 f = *(const float4*)(s + 4 * i);
        uint2 pk;
        pk.x = pk2(f2bf(f.x), f2bf(f.y));
        pk.y = pk2(f2bf(f.z), f2bf(f.w));
        *(uint2*)&Ts[chw][pxg + 4 * i] = pk;
      }
      __syncthreads();
      ushort g[16];
#pragma unroll
      for (int j = 0; j < 16; ++j) g[j] = Ts[chr + j][pxr];
      *(uint4*)(dst + (size_t)(p0 + pxr) * 32 + chr)     = *(uint4*)&g[0];
      *(uint4*)(dst + (size_t)(p0 + pxr) * 32 + chr + 8) = *(uint4*)&g[8];
    }
  } else if (blk < 1536) {
    // ---- pack_w (R6 body; global reads float4-vectorized, same mapping) ----
    float*  Ls = (float*)smem;                     // 18,432 B
    ushort* Lw = (ushort*)(smem + 18432);          // 36,864 B
    int idx = blk - 1024;
    int b = idx >> 3, ogrp = idx & 7;
    const float* gbase = q + (size_t)b * QSTRIDE + (size_t)ogrp * 16 * 1152;
    int o_loc = t >> 6;
    int ci    = (t & 63) * 2;
    int cq    = ci >> 5, coff = ci & 31;
    for (int r = 0; r < 4; ++r) {
      __syncthreads();
      const float4* gs4 = (const float4*)(gbase + r * 4608);
      float4* Ls4 = (float4*)Ls;
#pragma unroll
      for (int i = 0; i < 4; ++i) Ls4[i * 256 + t] = gs4[i * 256 + t];
      if (t < 128) Ls4[1024 + t] = gs4[1024 + t];
      __syncthreads();
      int o_in = r * 4 + o_loc;
      const float* v = Ls + o_loc * 1152 + ci * 9;
      float a[18];
#pragma unroll
      for (int i = 0; i < 18; ++i) a[i] = v[i];
#pragma unroll
      for (int tap = 0; tap < 9; ++tap) {
        unsigned pkv = pk2(f2bf(a[tap]), f2bf(a[9 + tap]));
        *(unsigned*)&Lw[((tap * 4 + cq) * 16 + o_in) * 32 + coff] = pkv;
      }
    }
    __syncthreads();
    int wv = t >> 6, l = t & 63;
    ushort* dstb = wt2 + (size_t)b * 147456 + (size_t)ogrp * 16 * 32;
#pragma unroll
    for (int tap = 0; tap < 9; ++tap) {
      const uint4 val = *(const uint4*)&Lw[(tap * 4 + wv) * 512 + l * 8];
      *(uint4*)(dstb + (size_t)(tap * 4 + wv) * 4096 + l * 8) = val;
    }
  } else {
    // ---- pack_pw (verified body) ----
    int tg = (blk - 1536) * 256 + t;
    int o  = tg >> 5;
    int c0 = (tg & 31) * 8;
    const float4* s4 = (const float4*)(pw + (size_t)o * 256 + c0);
    float4 f0 = s4[0], f1 = s4[1];
    uint4 pkv;
    pkv.x = pk2(f2bf(f0.x), f2bf(f0.y)); pkv.y = pk2(f2bf(f0.z), f2bf(f0.w));
    pkv.z = pk2(f2bf(f1.x), f2bf(f1.y)); pkv.w = pk2(f2bf(f1.z), f2bf(f1.w));
    *(uint4*)(pwb2 + (size_t)(c0 >> 5) * 4096 + o * 32 + (c0 & 31)) = pkv;
  }
}

// ---------------------------------------------------------------------------
// 2) FUSED proj+conv -- EXACT R6 version (measured 44.5 us, 2 blocks/CU).
//    phase 1: mini-proj GEMM; bg direct uint4 loads from xt (1KB/wave lines);
//             af from L2-hot pwb2. Result -> LDS Bs with halo zeroed.
//    phase 2: 3x3 conv, 9-tap barrier-free loop; A-frags from L2-hot wt2.
// ---------------------------------------------------------------------------
__global__ __launch_bounds__(256, 2) void fused_conv_kernel(const ushort* __restrict__ wt2,
                                                            const ushort* __restrict__ pwb2,
                                                            const ushort* __restrict__ xt,
                                                            const float* __restrict__ pb,
                                                            const float* __restrict__ q,
                                                            float* __restrict__ out) {
  __shared__ ushort Bs[4][6][34][32];        // 52,224 B
  int blk = blockIdx.x;
  int b = blk & 63, tile = blk >> 6;
  int p0 = tile * 128, h0 = tile * 4;
  int t = threadIdx.x;
  int lane = t & 63, wv = t >> 6;
  int quad = lane >> 4, li = lane & 15;

  // ---- col-halo zero: px 0 and 33 of every (cq, row) ----
  if (t < 48) {
    int cq = t & 3, side = (t >> 2) & 1, rr = t >> 3;   // rr 0..5
    uint4* z4 = (uint4*)&Bs[cq][rr][side ? 33 : 0][0];
    uint4 z; z.x = z.y = z.z = z.w = 0u;
    z4[0] = z; z4[1] = z; z4[2] = z; z4[3] = z;
  }

  // ---- phase 1: mini-proj into Bs ----
  {
    int rk[3], wk[3], hk[3]; bool lv[3];
#pragma unroll
    for (int k = 0; k < 3; ++k) {
      int nt = wv * 3 + k;
      rk[k] = nt >> 1;                       // Bs row 0..5
      wk[k] = (nt & 1) * 16;                 // w base 0 or 16
      hk[k] = h0 - 1 + rk[k];                // image row
      lv[k] = (hk[k] >= 0) && (hk[k] < 32);
    }
    const ushort* xtb = xt + (size_t)b * 8 * 32768;
    f32x4 acc[3][8] = {};
#pragma unroll
    for (int c = 0; c < 8; ++c) {            // 8 chunks of 32 channels
      bf16x8 bg[3];
#pragma unroll
      for (int k = 0; k < 3; ++k) {
        union { uint4 u; bf16x8 v; } bu;
        if (lv[k]) {
          int px = hk[k] * 32 + wk[k] + li;
          bu.u = *(const uint4*)(xtb + ((size_t)c * 1024 + px) * 32 + quad * 8);
        } else {
          bu.u.x = bu.u.y = bu.u.z = bu.u.w = 0u;
        }
        bg[k] = bu.v;
      }
      const ushort* ap = pwb2 + (size_t)c * 4096 + li * 32 + quad * 8;
#pragma unroll
      for (int mi = 0; mi < 8; ++mi) {
        bf16x8 af = *(const bf16x8*)(ap + mi * 512);   // reused for all 3 k
#pragma unroll
        for (int k = 0; k < 3; ++k)
          acc[k][mi] = __builtin_amdgcn_mfma_f32_16x16x32_bf16(af, bg[k], acc[k][mi], 0, 0, 0);
      }
    }
    // epilogue -> Bs (live rows: +bias; dead rows: zeros -- conv zero-padding)
#pragma unroll
    for (int k = 0; k < 3; ++k) {
#pragma unroll
      for (int mi = 0; mi < 8; ++mi) {
        int o0 = mi * 16 + quad * 4;
        uint2 pkv;
        if (lv[k]) {
          float4 bias = *(const float4*)(pb + o0);
          f32x4 a = acc[k][mi];
          pkv.x = pk2(f2bf(a.x + bias.x), f2bf(a.y + bias.y));
          pkv.y = pk2(f2bf(a.z + bias.z), f2bf(a.w + bias.w));
        } else {
          pkv.x = 0u; pkv.y = 0u;
        }
        *(uint2*)&Bs[o0 >> 5][rk[k]][wk[k] + li + 1][o0 & 31] = pkv;
      }
    }
  }
  __syncthreads();                           // Bs fully built & visible

  // ---- phase 2: 3x3 conv over Bs, A-frags from wt2 global (L2-hot) ----
  int m0 = (wv & 1) * 64, n0 = (wv >> 1) * 64;
  f32x4 acc2[4][4] = {};
  const ushort* wtb = wt2 + (size_t)b * 147456;
#pragma unroll
  for (int cq = 0; cq < 4; ++cq) {
    const ushort* wcq = wtb + (size_t)cq * 4096;
#pragma unroll
    for (int tap = 0; tap < 9; ++tap) {
      const ushort* ar = wcq + (size_t)tap * 16384;   // slab (tap*4+cq)*4096
      int kh = tap / 3, kw = tap - kh * 3;
      bf16x8 af[4], bg[4];
#pragma unroll
      for (int mi = 0; mi < 4; ++mi)
        af[mi] = *(const bf16x8*)(ar + (m0 + mi*16 + li) * 32 + quad * 8);
#pragma unroll
      for (int ni = 0; ni < 4; ++ni) {
        int pl = n0 + ni*16 + li;
        int hh = pl >> 5, ww = pl & 31;
        bg[ni] = *(const bf16x8*)&Bs[cq][hh + kh][ww + kw][quad * 8];
      }
#pragma unroll
      for (int mi = 0; mi < 4; ++mi)
#pragma unroll
        for (int ni = 0; ni < 4; ++ni)
          acc2[mi][ni] = __builtin_amdgcn_mfma_f32_16x16x32_bf16(af[mi], bg[ni], acc2[mi][ni], 0, 0, 0);
    }
  }

  const float* qb = q + (size_t)b * QSTRIDE + WOFF;
  float* ob = out + (size_t)b * 128 * 1024 + p0;
#pragma unroll
  for (int mi = 0; mi < 4; ++mi) {
    int o0 = m0 + mi*16 + quad*4;
    float4 bias = *(const float4*)(qb + o0);
#pragma unroll
    for (int ni = 0; ni < 4; ++ni) {
      int pl = n0 + ni*16 + li;
      float* dp = ob + (size_t)o0 * 1024 + pl;
      f32x4 a = acc2[mi][ni];
      dp[0]    = a.x + bias.x;
      dp[1024] = a.y + bias.y;
      dp[2048] = a.z + bias.z;
      dp[3072] = a.w + bias.w;
    }
  }
}

extern "C" void kernel_launch(void* const* d_in, const int* in_sizes, int n_in,
                              void* d_out, int out_size, void* d_ws, size_t ws_size,
                              hipStream_t stream) {
  const float* q   = (const float*)d_in[0];
  const float* lhs = (const float*)d_in[1];
  const float* rhs = (const float*)d_in[2];
  const float* pw  = (const float*)d_in[3];
  const float* pb  = (const float*)d_in[4];
  float* out = (float*)d_out;

  // workspace layout (52,494,336 B used)
  char* ws = (char*)d_ws;
  ushort* wt2  = (ushort*)(ws);               // 18,874,368 B : wt2[b][tap][cq][o][32]
  ushort* pwb2 = (ushort*)(ws + 18874368);    //     65,536 B : pwb2[chunk][o][32]
  ushort* xt   = (ushort*)(ws + 18939904);    // 33,554,432 B : xt[b][c8][px1024][ch32]

  prep_kernel      <<<1552, 256, 0, stream>>>(q, pw, lhs, rhs, wt2, pwb2, xt);
  fused_conv_kernel<<<512,  256, 0, stream>>>(wt2, pwb2, xt, pb, q, out);
}